// Round 1
// 862.876 us; speedup vs baseline: 2.3662x; 2.3662x over previous
//
#include <hip/hip_runtime.h>
#include <stdint.h>

// Problem constants
#define N_TOK 65536
#define DIN   512
#define DH    1024
#define DOUT  512
#define NE    8
#define MP_CAP 66560     // padded row space capacity (N + 8*128, /128)
#define ROW_BLOCKS 520   // MP_CAP / 128
#define CSTRIDE 144      // epilogue C-stage LDS row stride (ushorts): bank-conflict-free

typedef __bf16 bf16x8 __attribute__((ext_vector_type(8)));
typedef float  f32x4  __attribute__((ext_vector_type(4)));

// address-space-qualified pointer types for global_load_lds
typedef __attribute__((address_space(3))) void  lds_void;
typedef const __attribute__((address_space(1))) void g_void;

__device__ __forceinline__ float bf2f(unsigned short u) {
  union { unsigned int i; float f; } v; v.i = ((unsigned int)u) << 16; return v.f;
}
__device__ __forceinline__ unsigned short f2bf(float f) {
  unsigned int u = __builtin_bit_cast(unsigned int, f);
  u += 0x7fffu + ((u >> 16) & 1u);      // RNE
  return (unsigned short)(u >> 16);
}

// ---------------- dtype probe (fp32-read-as-ushort has wild exponents) ----------------
__global__ void detect_k(const unsigned short* __restrict__ x, int* __restrict__ flag) {
  __shared__ int cnt;
  if (threadIdx.x == 0) cnt = 0;
  __syncthreads();
  int c = 0;
  for (int i = threadIdx.x; i < 16384; i += 256) {
    const unsigned short u = x[2 * i];
    const int ex = (u >> 7) & 0xFF;
    if (ex > 140) ++c;
  }
  atomicAdd(&cnt, c);
  __syncthreads();
  if (threadIdx.x == 0) flag[0] = (cnt > 512) ? 1 : 0;   // 1 = inputs are fp32
}

// ---------------- canonicalize x -> bf16 xc (only needed when flag=1) ----------------
__global__ __launch_bounds__(256)
void conv_x_k(const void* __restrict__ xin, unsigned short* __restrict__ xc,
              const int* __restrict__ flag) {
  if (!flag[0]) return;                       // bf16 world: gemm reads x directly
  const int i = (blockIdx.x * 256 + threadIdx.x) * 8;
  const float* xf = (const float*)xin;
  unsigned short o[8];
#pragma unroll
  for (int j = 0; j < 8; ++j) o[j] = f2bf(xf[i + j]);
  *(uint4*)&xc[i] = *(const uint4*)o;
}

// ---------------- biases -> fp32 ----------------
__global__ void conv_bias_k(const void* __restrict__ b, float* __restrict__ out, int n,
                            const int* __restrict__ flag) {
  const int i = blockIdx.x * 256 + threadIdx.x;
  if (i < n) out[i] = flag[0] ? ((const float*)b)[i] : bf2f(((const unsigned short*)b)[i]);
}

// ---------------- weight transpose: W[e][K][Nn] -> WT[e][Nn][K] (bf16 out) ----------------
__global__ __launch_bounds__(1024)
void transpose_k(const void* __restrict__ W, unsigned short* __restrict__ WT,
                 int K, int Nn, const int* __restrict__ flag) {
  __shared__ unsigned short tile[64][65];
  const int fv = flag[0];
  const int e = blockIdx.z;
  const size_t base = (size_t)e * K * Nn;
  unsigned short* dst = WT + base;
  const int n0 = blockIdx.x * 64, k0 = blockIdx.y * 64;
  const int tx = threadIdx.x, ty = threadIdx.y;
#pragma unroll
  for (int i = 0; i < 4; ++i) {
    const size_t idx = base + (size_t)(k0 + ty + i * 16) * Nn + n0 + tx;
    tile[ty + i * 16][tx] = fv ? f2bf(((const float*)W)[idx])
                               : ((const unsigned short*)W)[idx];
  }
  __syncthreads();
#pragma unroll
  for (int i = 0; i < 4; ++i)
    dst[(size_t)(n0 + ty + i * 16) * K + k0 + tx] = tile[tx][ty + i * 16];
}

// ---------------- gating: one wave per token, fp64 accumulate ----------------
__global__ __launch_bounds__(256)
void gating_k(const void* __restrict__ x, const void* __restrict__ Wg,
              const void* __restrict__ bg, int* __restrict__ eidx,
              const int* __restrict__ flag) {
  const int wv = threadIdx.x >> 6, lane = threadIdx.x & 63;
  const int t = blockIdx.x * 4 + wv;
  const int fv = flag[0];
  double acc[8];
#pragma unroll
  for (int e = 0; e < 8; ++e) acc[e] = 0.0;
  if (fv) {
    const float* xr = (const float*)x + (size_t)t * DIN;
    const float* wg = (const float*)Wg;
#pragma unroll
    for (int i = 0; i < 8; ++i) {
      const int k = i * 64 + lane;
      const double xv = (double)xr[k];
#pragma unroll
      for (int e = 0; e < 8; ++e) acc[e] += xv * (double)wg[(size_t)k * 8 + e];
    }
  } else {
    const unsigned short* xr = (const unsigned short*)x + (size_t)t * DIN;
    const unsigned short* wg = (const unsigned short*)Wg;
#pragma unroll
    for (int i = 0; i < 8; ++i) {
      const int k = i * 64 + lane;
      const double xv = (double)bf2f(xr[k]);
      const uint4 wq = *(const uint4*)(wg + (size_t)k * 8);
      acc[0] += xv * (double)bf2f((unsigned short)(wq.x & 0xffff));
      acc[1] += xv * (double)bf2f((unsigned short)(wq.x >> 16));
      acc[2] += xv * (double)bf2f((unsigned short)(wq.y & 0xffff));
      acc[3] += xv * (double)bf2f((unsigned short)(wq.y >> 16));
      acc[4] += xv * (double)bf2f((unsigned short)(wq.z & 0xffff));
      acc[5] += xv * (double)bf2f((unsigned short)(wq.z >> 16));
      acc[6] += xv * (double)bf2f((unsigned short)(wq.w & 0xffff));
      acc[7] += xv * (double)bf2f((unsigned short)(wq.w >> 16));
    }
  }
#pragma unroll
  for (int o = 32; o > 0; o >>= 1)
#pragma unroll
    for (int e = 0; e < 8; ++e) acc[e] += __shfl_down(acc[e], o, 64);
  if (lane == 0) {
    int bi = 0;
    double best = acc[0] + (double)(fv ? ((const float*)bg)[0]
                                       : bf2f(((const unsigned short*)bg)[0]));
#pragma unroll
    for (int e = 1; e < 8; ++e) {
      const double v = acc[e] + (double)(fv ? ((const float*)bg)[e]
                                            : bf2f(((const unsigned short*)bg)[e]));
      if (v > best) { best = v; bi = e; }   // strict >: first-max wins (np.argmax)
    }
    eidx[t] = bi;
  }
}

// ---------------- per-block histogram -> global counts ----------------
__global__ __launch_bounds__(256)
void count_k(const int* __restrict__ eidx, int* __restrict__ counts) {
  __shared__ int h[8];
  if (threadIdx.x < 8) h[threadIdx.x] = 0;
  __syncthreads();
  atomicAdd(&h[eidx[blockIdx.x * 256 + threadIdx.x]], 1);
  __syncthreads();
  if (threadIdx.x < 8) atomicAdd(&counts[threadIdx.x], h[threadIdx.x]);
}

// ---------------- padded prefix offsets ----------------
__global__ void offsets_k(const int* __restrict__ counts, int* __restrict__ off,
                          int* __restrict__ fill) {
  if (threadIdx.x == 0) {
    int a = 0;
    off[0] = 0;
    for (int e = 0; e < 8; ++e) {
      a += (counts[e] + 127) & ~127;
      off[e + 1] = a;
    }
  }
  if (threadIdx.x < 8) fill[threadIdx.x] = 0;
}

// ---------------- scatter tokens into rowmap ----------------
__global__ __launch_bounds__(256)
void scatter_k(const int* __restrict__ eidx, const int* __restrict__ off,
               int* __restrict__ fill, int* __restrict__ rowmap) {
  const int t = blockIdx.x * 256 + threadIdx.x;
  const int lane = threadIdx.x & 63;
  const int e = eidx[t];
#pragma unroll
  for (int ex = 0; ex < 8; ++ex) {
    unsigned long long m = __ballot(e == ex);
    if (e == ex) {
      const unsigned long long lt = (1ULL << lane) - 1ULL;
      const int rank = __popcll(m & lt);
      const int leader = __ffsll((unsigned long long)m) - 1;
      int base = 0;
      if (lane == leader) base = atomicAdd(&fill[ex], (int)__popcll(m));
      base = __shfl(base, leader, 64);
      rowmap[off[ex] + base + rank] = t;
    }
  }
}

// ---------------- grouped GEMM: C[128 x 128] per block, K-step 64 ----------------
// 1-D grid with XCD-aware swizzle: all ncb column-blocks of one row-group land on the
// same XCD (blockIdx % 8) back-to-back, so the A-tile is L2-resident for its re-reads.
// Staging: global_load_lds width=16 (async, no VGPR round-trip). The XOR-swizzled LDS
// layout is preserved via Rule 21: LINEAR LDS dest (wave-uniform base + lane*16) +
// INVERSE-swizzled PER-LANE global source chunk (q ^ subrow), so LDS contents are
// bit-identical to the old reg-staged path and the ds_read side is unchanged.
// Epilogue: acc -> LDS (stride CSTRIDE, conflict-free) -> coalesced uint4 stores.
template <int GATHER, int RELU, int SCATTER>
__global__ __launch_bounds__(256, 2)
void gemm_k(const unsigned short* __restrict__ A, const unsigned short* __restrict__ Axc,
            const unsigned short* __restrict__ BT,
            const float* __restrict__ biasF, void* __restrict__ C,
            const int* __restrict__ rowmap, const int* __restrict__ off,
            const int* __restrict__ flag, const int K, const int Nc, const int rowBase,
            const int ncb, const int lncb) {
  __shared__ __align__(16) unsigned short smem[128 * CSTRIDE];  // 36 KB
  unsigned short* As = smem;                 // staging: 128x64 = 16 KB
  unsigned short* Bs = smem + 128 * 64;      // staging: 128x64 = 16 KB

  // ---- swizzled block -> (rowg, col) ----
  const int segBlocksLocal = gridDim.x >> lncb;
  const int fullRows = segBlocksLocal & ~7;
  const int fullBlocks = fullRows << lncb;
  int col, rowg;
  {
    const int p = blockIdx.x;
    if (p < fullBlocks) {
      const int xcd = p & 7, qq = p >> 3;
      col = qq & (ncb - 1);
      rowg = ((qq >> lncb) << 3) + xcd;
    } else {
      const int r = p - fullBlocks;
      col = r & (ncb - 1);
      rowg = fullRows + (r >> lncb);
    }
  }

  const int Mp = off[8];
  const int rowStart = rowBase + rowg * 128;
  if (rowStart >= Mp) return;
  int e = 0;
#pragma unroll
  for (int j = 1; j <= 8; ++j) e += (off[j] <= rowStart) ? 1 : 0;

  const int colStart = col * 128;
  const int tid = threadIdx.x;
  const int w = tid >> 6, lane = tid & 63;
  const int subrow = lane >> 3;
  const int q = lane & 7;
  const int slot = q ^ subrow;               // inverse-swizzled global chunk index

  const unsigned short* Ause = (GATHER && flag[0]) ? Axc : A;
  const unsigned short* Be = BT + (size_t)e * Nc * K;

  // per-lane global source pointers (chunk `slot`), wave-uniform LDS dest offsets
  const unsigned short* aptr[4];
  const unsigned short* bptr[4];
  int ldsOff[4];
#pragma unroll
  for (int i = 0; i < 4; ++i) {
    const int r = i * 32 + w * 8 + subrow;
    int arow;
    if (GATHER) {
      arow = rowmap[rowStart + r];
      if (arow < 0) arow = 0;                 // padding row: load safe garbage
    } else {
      arow = rowStart + r - rowBase;          // segment-local
    }
    aptr[i] = Ause + (size_t)arow * K + slot * 8;
    bptr[i] = Be + (size_t)(colStart + r) * K + slot * 8;
    ldsOff[i] = (i * 32 + w * 8) * 64;        // linear dest: 8 rows x 128 B per call
  }

  const int wm = w >> 1, wn = w & 1;
  const int fr = lane & 15, quad = lane >> 4;

  f32x4 acc[4][4];
#pragma unroll
  for (int i = 0; i < 4; ++i)
#pragma unroll
    for (int j = 0; j < 4; ++j) acc[i][j] = (f32x4){0.f, 0.f, 0.f, 0.f};

  int aoff[2][4], boff[2][4];
#pragma unroll
  for (int s = 0; s < 2; ++s)
#pragma unroll
    for (int i = 0; i < 4; ++i) {
      const int qq = quad + s * 4;
      const int rowA = wm * 64 + i * 16 + fr;
      aoff[s][i] = rowA * 64 + (qq ^ (rowA & 7)) * 8;
      const int rowB = wn * 64 + i * 16 + fr;
      boff[s][i] = rowB * 64 + (qq ^ (rowB & 7)) * 8;
    }

  for (int k0 = 0; k0 < K; k0 += 64) {
    // async global -> LDS staging (this K-step's tile). Prior iteration's trailing
    // barrier guarantees all LDS reads of the previous tile completed.
#pragma unroll
    for (int i = 0; i < 4; ++i) {
      __builtin_amdgcn_global_load_lds((g_void*)(aptr[i] + k0),
                                       (lds_void*)(As + ldsOff[i]), 16, 0, 0);
      __builtin_amdgcn_global_load_lds((g_void*)(bptr[i] + k0),
                                       (lds_void*)(Bs + ldsOff[i]), 16, 0, 0);
    }
    __syncthreads();                          // vmcnt(0) drain -> tile visible to all
    bf16x8 af[2][4], bfv[2][4];
#pragma unroll
    for (int s = 0; s < 2; ++s)
#pragma unroll
      for (int i = 0; i < 4; ++i) {
        af[s][i] = *(const bf16x8*)&As[aoff[s][i]];
        bfv[s][i] = *(const bf16x8*)&Bs[boff[s][i]];
      }
#pragma unroll
    for (int s = 0; s < 2; ++s)
#pragma unroll
      for (int i = 0; i < 4; ++i)
#pragma unroll
        for (int j = 0; j < 4; ++j)
          acc[i][j] = __builtin_amdgcn_mfma_f32_16x16x32_bf16(af[s][i], bfv[s][j],
                                                              acc[i][j], 0, 0, 0);
    __syncthreads();                          // reads done before next overwrite
  }

  // ---- epilogue ----
  const int flagv = SCATTER ? flag[0] : 0;
  float bv2[4];
#pragma unroll
  for (int j = 0; j < 4; ++j)
    bv2[j] = biasF[(size_t)e * Nc + colStart + wn * 64 + j * 16 + fr];

  if (SCATTER && flagv) {
    // rare fp32-output path: exact scalar stores from acc
#pragma unroll
    for (int i = 0; i < 4; ++i)
#pragma unroll
      for (int r = 0; r < 4; ++r) {
        const int gr = rowStart + wm * 64 + i * 16 + quad * 4 + r;
        const int crow = rowmap[gr];
        if (crow < 0) continue;
        const size_t cbase = (size_t)crow * Nc + colStart + wn * 64 + fr;
#pragma unroll
        for (int j = 0; j < 4; ++j)
          ((float*)C)[cbase + j * 16] = acc[i][j][r] + bv2[j];
      }
    return;
  }

#pragma unroll
  for (int i = 0; i < 4; ++i)
#pragma unroll
    for (int r = 0; r < 4; ++r) {
      const int row = wm * 64 + i * 16 + quad * 4 + r;   // C/D: row=(lane>>4)*4+reg
#pragma unroll
      for (int j = 0; j < 4; ++j) {
        float v = acc[i][j][r] + bv2[j];
        if (RELU) v = fmaxf(v, 0.f);
        smem[row * CSTRIDE + wn * 64 + j * 16 + fr] = f2bf(v);
      }
    }
  __syncthreads();

#pragma unroll
  for (int it = 0; it < 8; ++it) {
    const int idx = it * 256 + tid;
    const int row = idx >> 4, c16 = idx & 15;
    int crow;
    if (SCATTER) {
      crow = rowmap[rowStart + row];
      if (crow < 0) continue;                 // padding row
    } else {
      crow = rowStart + row - rowBase;        // segment-local
    }
    const uint4 vv = *(const uint4*)&smem[row * CSTRIDE + c16 * 8];
    *(uint4*)&((unsigned short*)C)[(size_t)crow * Nc + colStart + c16 * 8] = vv;
  }
}

extern "C" void kernel_launch(void* const* d_in, const int* in_sizes, int n_in,
                              void* d_out, int out_size, void* d_ws, size_t ws_size,
                              hipStream_t stream) {
  const void* x  = d_in[0];
  const void* Wg = d_in[1];
  const void* bg = d_in[2];
  const void* W0 = d_in[3];
  const void* b0 = d_in[4];
  const void* W1 = d_in[5];
  const void* b1 = d_in[6];
  const void* W2 = d_in[7];
  const void* b2 = d_in[8];

  char* ws = (char*)d_ws;
  // fixed workspace layout (~101.3 MB) + adaptive h0/h1
  unsigned short* WT0 = (unsigned short*)(ws + 0);            //  8 MB [E][DH][DIN]
  unsigned short* WT1 = (unsigned short*)(ws + 8388608);      // 16 MB [E][DH][DH]
  unsigned short* WT2 = (unsigned short*)(ws + 25165824);     //  8 MB [E][DOUT][DH]
  unsigned short* xc  = (unsigned short*)(ws + 33554432);     // 64 MB [N][DIN] bf16 (flag=1 only)
  float* bf0 = (float*)(ws + 100663296);
  float* bf1 = (float*)(ws + 100696064);
  float* bf2 = (float*)(ws + 100728832);
  int* rowmap = (int*)(ws + 100745216);                       // MP_CAP ints
  int* eidx   = (int*)(ws + 101011456);                       // N ints
  int* counts = (int*)(ws + 101273600);
  int* off    = (int*)(ws + 101273664);
  int* fill   = (int*)(ws + 101273728);
  int* flag   = (int*)(ws + 101273792);
  const size_t FIXED = 101274624;
  unsigned short* h0 = (unsigned short*)(ws + FIXED);

  // segment sizing: h0+h1 = segBlocks * 524288 B; prefer multiples of 8 for the swizzle
  int segBlocks = 1;
  if (ws_size > FIXED + 524288) {
    size_t sb = (ws_size - FIXED) / 524288;
    segBlocks = (sb > ROW_BLOCKS) ? ROW_BLOCKS : (int)sb;
    if (segBlocks >= 8) segBlocks &= ~7;
  }
  unsigned short* h1 = h0 + (size_t)segBlocks * 128 * DH;
  const int nseg = (ROW_BLOCKS + segBlocks - 1) / segBlocks;

  hipMemsetAsync(counts, 0, 8 * sizeof(int), stream);
  hipMemsetAsync(rowmap, 0xFF, MP_CAP * sizeof(int), stream);   // -1 = padding

  detect_k<<<1, 256, 0, stream>>>((const unsigned short*)x, flag);

  conv_x_k<<<N_TOK * DIN / 8 / 256, 256, 0, stream>>>(x, xc, flag);
  conv_bias_k<<<(NE * DH + 255) / 256, 256, 0, stream>>>(b0, bf0, NE * DH, flag);
  conv_bias_k<<<(NE * DH + 255) / 256, 256, 0, stream>>>(b1, bf1, NE * DH, flag);
  conv_bias_k<<<(NE * DOUT + 255) / 256, 256, 0, stream>>>(b2, bf2, NE * DOUT, flag);

  transpose_k<<<dim3(DH / 64, DIN / 64, NE), dim3(64, 16), 0, stream>>>(W0, WT0, DIN, DH, flag);
  transpose_k<<<dim3(DH / 64, DH / 64, NE), dim3(64, 16), 0, stream>>>(W1, WT1, DH, DH, flag);
  transpose_k<<<dim3(DOUT / 64, DH / 64, NE), dim3(64, 16), 0, stream>>>(W2, WT2, DH, DOUT, flag);

  gating_k<<<N_TOK / 4, 256, 0, stream>>>(x, Wg, bg, eidx, flag);
  count_k<<<N_TOK / 256, 256, 0, stream>>>(eidx, counts);
  offsets_k<<<1, 64, 0, stream>>>(counts, off, fill);
  scatter_k<<<N_TOK / 256, 256, 0, stream>>>(eidx, off, fill, rowmap);

  for (int s = 0; s < nseg; ++s) {
    const int rowBase = s * segBlocks * 128;
    // layer 0: gather x rows -> h0 (relu); ncb = DH/128 = 8
    gemm_k<1, 1, 0><<<dim3(8 * segBlocks), 256, 0, stream>>>(
        (const unsigned short*)x, xc, WT0, bf0, h0, rowmap, off, flag, DIN, DH, rowBase, 8, 3);
    // layer 1: h0 -> h1 (relu); ncb = 8
    gemm_k<0, 1, 0><<<dim3(8 * segBlocks), 256, 0, stream>>>(
        h0, h0, WT1, bf1, h1, rowmap, off, flag, DH, DH, rowBase, 8, 3);
    // layer 2: h1 -> out (scatter, bias only); ncb = DOUT/128 = 4
    gemm_k<0, 0, 1><<<dim3(4 * segBlocks), 256, 0, stream>>>(
        h1, h1, WT2, bf2, d_out, rowmap, off, flag, DH, DOUT, rowBase, 4, 2);
  }
}